// Round 1
// baseline (106.954 us; speedup 1.0000x reference)
//
#include <hip/hip_runtime.h>
#include <cmath>

// Cox partial likelihood (Breslow) loss, N=16384.
// denom[i] = sum_j [t_j >= t_i] * exp(est_j)
// loss = sum_i ev_i * (log(denom[i]) - est[i]) / max(sum ev, 1)

#define CHUNKS 8      // j-chunks per block (one wave each)
#define IB     64     // i's per block (= one wave of lanes)

// ---------------------------------------------------------------------------
// Kernel 1: stage t (contiguous) and e = exp(est) into workspace.
__global__ void cox_prep(const float* __restrict__ est,
                         const float* __restrict__ target,
                         float* __restrict__ t,
                         float* __restrict__ e,
                         int n) {
    int j = blockIdx.x * blockDim.x + threadIdx.x;
    if (j < n) {
        t[j] = target[2 * j];
        e[j] = expf(est[j]);
    }
}

// ---------------------------------------------------------------------------
// Kernel 2: per-block denom + partial loss/event reduction.
// Block = 512 threads = 8 waves. Lane (tid&63) owns i = blockIdx*64 + lane.
// Wave w scans j-chunk w (wave-uniform j -> scalar-load friendly).
__global__ __launch_bounds__(IB * CHUNKS)
void cox_denom(const float* __restrict__ est,
               const float* __restrict__ target,
               const float* __restrict__ t,
               const float* __restrict__ e,
               float* __restrict__ ploss,
               float* __restrict__ pev,
               int n) {
    __shared__ float sden[CHUNKS][IB];

    const int tid   = threadIdx.x;
    const int il    = tid & (IB - 1);
    // tid>>6 is the wave id -- force the compiler to treat it as uniform so
    // the t[j]/e[j] loads below scalarize (SMEM path, VALU stays the bottleneck).
    const int chunk = __builtin_amdgcn_readfirstlane(tid >> 6);
    const int i     = blockIdx.x * IB + il;

    const float ti = (i < n) ? t[i] : 3.0e38f;  // ti=+big -> mask never hits

    const int cj = (n + CHUNKS - 1) / CHUNKS;
    const int j0 = chunk * cj;
    const int j1 = min(j0 + cj, n);

    // 4 independent accumulators to break the dependent-add chain.
    float a0 = 0.f, a1 = 0.f, a2 = 0.f, a3 = 0.f;
    int j = j0;
    for (; j + 3 < j1; j += 4) {
        float t0 = t[j],     e0 = e[j];
        float t1 = t[j + 1], e1 = e[j + 1];
        float t2 = t[j + 2], e2 = e[j + 2];
        float t3 = t[j + 3], e3 = e[j + 3];
        a0 += (ti <= t0) ? e0 : 0.f;
        a1 += (ti <= t1) ? e1 : 0.f;
        a2 += (ti <= t2) ? e2 : 0.f;
        a3 += (ti <= t3) ? e3 : 0.f;
    }
    for (; j < j1; ++j)
        a0 += (ti <= t[j]) ? e[j] : 0.f;

    sden[chunk][il] = (a0 + a1) + (a2 + a3);
    __syncthreads();

    // Wave 0 finishes: reduce chunks, compute per-i contribution, wave-reduce.
    if (tid < IB) {
        float d = 0.f;
        #pragma unroll
        for (int c = 0; c < CHUNKS; ++c) d += sden[c][tid];

        float contrib = 0.f, ev = 0.f;
        if (i < n) {
            ev      = (target[2 * i + 1] != 0.f) ? 1.f : 0.f;
            contrib = ev * (logf(d) - est[i]);
        }
        #pragma unroll
        for (int off = 32; off > 0; off >>= 1) {
            contrib += __shfl_down(contrib, off, 64);
            ev      += __shfl_down(ev, off, 64);
        }
        if (tid == 0) {
            ploss[blockIdx.x] = contrib;
            pev[blockIdx.x]   = ev;
        }
    }
}

// ---------------------------------------------------------------------------
// Kernel 3: final reduction of block partials -> scalar loss.
__global__ void cox_finalize(const float* __restrict__ ploss,
                             const float* __restrict__ pev,
                             float* __restrict__ out,
                             int nblocks) {
    const int tid = threadIdx.x;  // 64 threads = one wave
    float l = 0.f, v = 0.f;
    for (int k = tid; k < nblocks; k += 64) {
        l += ploss[k];
        v += pev[k];
    }
    #pragma unroll
    for (int off = 32; off > 0; off >>= 1) {
        l += __shfl_down(l, off, 64);
        v += __shfl_down(v, off, 64);
    }
    if (tid == 0) out[0] = l / fmaxf(v, 1.f);
}

// ---------------------------------------------------------------------------
extern "C" void kernel_launch(void* const* d_in, const int* in_sizes, int n_in,
                              void* d_out, int out_size, void* d_ws, size_t ws_size,
                              hipStream_t stream) {
    const float* est    = (const float*)d_in[0];
    const float* target = (const float*)d_in[1];
    float*       out    = (float*)d_out;

    const int n = in_sizes[0];                 // 16384
    const int nblocks = (n + IB - 1) / IB;     // 256 i-blocks

    float* ws    = (float*)d_ws;
    float* t     = ws;                 // [n]
    float* e     = ws + n;             // [n]
    float* ploss = ws + 2 * n;         // [nblocks]
    float* pev   = ploss + nblocks;    // [nblocks]

    cox_prep<<<(n + 255) / 256, 256, 0, stream>>>(est, target, t, e, n);
    cox_denom<<<nblocks, IB * CHUNKS, 0, stream>>>(est, target, t, e, ploss, pev, n);
    cox_finalize<<<1, 64, 0, stream>>>(ploss, pev, out, nblocks);
}

// Round 2
// 54.113 us; speedup vs baseline: 1.9765x; 1.9765x over previous
//
#include <hip/hip_runtime.h>
#include <cmath>

// Cox partial likelihood (Breslow) loss, N=16384.
// denom[i] = sum_j [t_j >= t_i] * exp(est_j)
// loss = sum_i ev_i * (log(denom[i]) - est[i]) / max(sum ev, 1)

#define CHUNKS 8      // waves per block (each scans a j-subchunk)
#define IB     64     // i's per block (= one wave of lanes)
#define JSPLIT 4      // j-range split across blockIdx.y -> 4x more blocks

// ---------------------------------------------------------------------------
// Kernel 1: stage t (contiguous) and e = exp(est) into workspace.
__global__ void cox_prep(const float* __restrict__ est,
                         const float* __restrict__ target,
                         float* __restrict__ t,
                         float* __restrict__ e,
                         int n) {
    int j = blockIdx.x * blockDim.x + threadIdx.x;
    if (j < n) {
        t[j] = target[2 * j];
        e[j] = expf(est[j]);
    }
}

// ---------------------------------------------------------------------------
// Kernel 2: partial denom over this block's j-range.
// Block = 512 threads = 8 waves. Lane (tid&63) owns i = blockIdx.x*64 + lane.
// Wave w scans j-subchunk w of j-range blockIdx.y (wave-uniform j -> scalar
// loads). 1024 blocks -> 8 waves/SIMD -> latency fully hidden.
__global__ __launch_bounds__(IB * CHUNKS)
void cox_denom(const float* __restrict__ t,
               const float* __restrict__ e,
               float* __restrict__ pden,   // [JSPLIT][n]
               int n) {
    __shared__ float sden[CHUNKS][IB];

    const int tid   = threadIdx.x;
    const int il    = tid & (IB - 1);
    const int chunk = __builtin_amdgcn_readfirstlane(tid >> 6);
    const int i     = blockIdx.x * IB + il;

    const float ti = (i < n) ? t[i] : 3.0e38f;  // ti=+big -> mask never hits

    // this block's j-range, then this wave's subchunk
    const int jr  = n / JSPLIT;                       // 4096
    const int jrb = blockIdx.y * jr;
    const int cj  = jr / CHUNKS;                      // 512
    const int j0  = jrb + chunk * cj;
    const int j1  = j0 + cj;

    // 4 independent accumulators to break the dependent-add chain.
    float a0 = 0.f, a1 = 0.f, a2 = 0.f, a3 = 0.f;
    for (int j = j0; j < j1; j += 4) {
        float t0 = t[j],     e0 = e[j];
        float t1 = t[j + 1], e1 = e[j + 1];
        float t2 = t[j + 2], e2 = e[j + 2];
        float t3 = t[j + 3], e3 = e[j + 3];
        a0 += (ti <= t0) ? e0 : 0.f;
        a1 += (ti <= t1) ? e1 : 0.f;
        a2 += (ti <= t2) ? e2 : 0.f;
        a3 += (ti <= t3) ? e3 : 0.f;
    }

    sden[chunk][il] = (a0 + a1) + (a2 + a3);
    __syncthreads();

    if (tid < IB) {
        float d = 0.f;
        #pragma unroll
        for (int c = 0; c < CHUNKS; ++c) d += sden[c][tid];
        if (i < n) pden[blockIdx.y * n + i] = d;
    }
}

// ---------------------------------------------------------------------------
// Kernel 3: combine j-split partials, per-i contribution, per-block reduce.
__global__ __launch_bounds__(256)
void cox_combine(const float* __restrict__ est,
                 const float* __restrict__ target,
                 const float* __restrict__ pden,
                 float* __restrict__ ploss,
                 float* __restrict__ pev,
                 int n) {
    __shared__ float sl[4], sv[4];
    const int tid = threadIdx.x;
    const int i   = blockIdx.x * 256 + tid;

    float contrib = 0.f, ev = 0.f;
    if (i < n) {
        float d = 0.f;
        #pragma unroll
        for (int s = 0; s < JSPLIT; ++s) d += pden[s * n + i];
        ev      = (target[2 * i + 1] != 0.f) ? 1.f : 0.f;
        contrib = ev * (logf(d) - est[i]);
    }
    #pragma unroll
    for (int off = 32; off > 0; off >>= 1) {
        contrib += __shfl_down(contrib, off, 64);
        ev      += __shfl_down(ev, off, 64);
    }
    if ((tid & 63) == 0) { sl[tid >> 6] = contrib; sv[tid >> 6] = ev; }
    __syncthreads();
    if (tid == 0) {
        ploss[blockIdx.x] = sl[0] + sl[1] + sl[2] + sl[3];
        pev[blockIdx.x]   = sv[0] + sv[1] + sv[2] + sv[3];
    }
}

// ---------------------------------------------------------------------------
// Kernel 4: final reduction of block partials -> scalar loss.
__global__ void cox_finalize(const float* __restrict__ ploss,
                             const float* __restrict__ pev,
                             float* __restrict__ out,
                             int nblocks) {
    const int tid = threadIdx.x;  // 64 threads = one wave
    float l = 0.f, v = 0.f;
    for (int k = tid; k < nblocks; k += 64) {
        l += ploss[k];
        v += pev[k];
    }
    #pragma unroll
    for (int off = 32; off > 0; off >>= 1) {
        l += __shfl_down(l, off, 64);
        v += __shfl_down(v, off, 64);
    }
    if (tid == 0) out[0] = l / fmaxf(v, 1.f);
}

// ---------------------------------------------------------------------------
extern "C" void kernel_launch(void* const* d_in, const int* in_sizes, int n_in,
                              void* d_out, int out_size, void* d_ws, size_t ws_size,
                              hipStream_t stream) {
    const float* est    = (const float*)d_in[0];
    const float* target = (const float*)d_in[1];
    float*       out    = (float*)d_out;

    const int n        = in_sizes[0];              // 16384
    const int niblocks = (n + IB - 1) / IB;        // 256 i-blocks
    const int ncblocks = (n + 255) / 256;          // 64 combine blocks

    float* ws    = (float*)d_ws;
    float* t     = ws;                    // [n]
    float* e     = ws + n;                // [n]
    float* pden  = ws + 2 * n;            // [JSPLIT][n]
    float* ploss = pden + JSPLIT * n;     // [ncblocks]
    float* pev   = ploss + ncblocks;      // [ncblocks]

    cox_prep<<<(n + 255) / 256, 256, 0, stream>>>(est, target, t, e, n);
    dim3 grid(niblocks, JSPLIT);
    cox_denom<<<grid, IB * CHUNKS, 0, stream>>>(t, e, pden, n);
    cox_combine<<<ncblocks, 256, 0, stream>>>(est, target, pden, ploss, pev, n);
    cox_finalize<<<1, 64, 0, stream>>>(ploss, pev, out, ncblocks);
}

// Round 3
// 46.489 us; speedup vs baseline: 2.3006x; 1.1640x over previous
//
#include <hip/hip_runtime.h>
#include <cmath>

// Cox partial likelihood (Breslow) loss, N=16384.
// denom[i] = sum_j [t_j >= t_i] * exp(est_j)
// loss = sum_i ev_i * (log(denom[i]) - est[i]) / max(sum ev, 1)

#define CHUNKS 8      // waves per block (each scans a j-subchunk)
#define IB     64     // i's per block (= one wave of lanes)
#define JSPLIT 4      // j-range split across blockIdx.y
#define UNROLL 16     // j's per inner iteration (2x s_load_dwordx16)

// ---------------------------------------------------------------------------
// Kernel 1: stage t (contiguous), and interleaved (t, exp(est)) pairs.
__global__ void cox_prep(const float* __restrict__ est,
                         const float* __restrict__ target,
                         float* __restrict__ t,
                         float2* __restrict__ te,
                         int n) {
    int j = blockIdx.x * blockDim.x + threadIdx.x;
    if (j < n) {
        float tj = target[2 * j];
        float ej = expf(est[j]);
        t[j]  = tj;
        te[j] = make_float2(tj, ej);
    }
}

// ---------------------------------------------------------------------------
// Kernel 2: partial denom over this block's j-range.
// Block = 512 threads = 8 waves. Lane (tid&63) owns i = blockIdx.x*64 + lane.
// Wave w scans j-subchunk w of j-range blockIdx.y. j is wave-uniform ->
// te[j] scalarizes to s_load_dwordx16 batches; UNROLL=16 gives 96 VALU
// cycles/wave per load batch so 8 waves/SIMD fully hide ~200cy SMEM latency.
__global__ __launch_bounds__(IB * CHUNKS)
void cox_denom(const float* __restrict__ t,
               const float2* __restrict__ te,
               float* __restrict__ pden,   // [JSPLIT][n]
               int n) {
    __shared__ float sden[CHUNKS][IB];

    const int tid   = threadIdx.x;
    const int il    = tid & (IB - 1);
    const int chunk = __builtin_amdgcn_readfirstlane(tid >> 6);
    const int i     = blockIdx.x * IB + il;

    const float ti = t[i];   // per-lane vector load (i < n always: n = grid*64)

    // this block's j-range, then this wave's subchunk
    const int jr  = n / JSPLIT;                       // 4096
    const int jrb = blockIdx.y * jr;
    const int cj  = jr / CHUNKS;                      // 512 (divisible by 16)
    const int j0  = jrb + chunk * cj;
    const int j1  = j0 + cj;

    float acc0 = 0.f, acc1 = 0.f, acc2 = 0.f, acc3 = 0.f;
    for (int j = j0; j < j1; j += UNROLL) {
        float2 v[UNROLL];
        #pragma unroll
        for (int u = 0; u < UNROLL; ++u) v[u] = te[j + u];
        #pragma unroll
        for (int u = 0; u < UNROLL; u += 4) {
            acc0 += (ti <= v[u + 0].x) ? v[u + 0].y : 0.f;
            acc1 += (ti <= v[u + 1].x) ? v[u + 1].y : 0.f;
            acc2 += (ti <= v[u + 2].x) ? v[u + 2].y : 0.f;
            acc3 += (ti <= v[u + 3].x) ? v[u + 3].y : 0.f;
        }
    }

    sden[chunk][il] = (acc0 + acc1) + (acc2 + acc3);
    __syncthreads();

    if (tid < IB) {
        float d = 0.f;
        #pragma unroll
        for (int c = 0; c < CHUNKS; ++c) d += sden[c][tid];
        pden[blockIdx.y * n + i] = d;
    }
}

// ---------------------------------------------------------------------------
// Kernel 3: combine j-split partials, per-i contribution, per-block reduce.
__global__ __launch_bounds__(256)
void cox_combine(const float* __restrict__ est,
                 const float* __restrict__ target,
                 const float* __restrict__ pden,
                 float* __restrict__ ploss,
                 float* __restrict__ pev,
                 int n) {
    __shared__ float sl[4], sv[4];
    const int tid = threadIdx.x;
    const int i   = blockIdx.x * 256 + tid;

    float contrib = 0.f, ev = 0.f;
    if (i < n) {
        float d = 0.f;
        #pragma unroll
        for (int s = 0; s < JSPLIT; ++s) d += pden[s * n + i];
        ev      = (target[2 * i + 1] != 0.f) ? 1.f : 0.f;
        contrib = ev * (logf(d) - est[i]);
    }
    #pragma unroll
    for (int off = 32; off > 0; off >>= 1) {
        contrib += __shfl_down(contrib, off, 64);
        ev      += __shfl_down(ev, off, 64);
    }
    if ((tid & 63) == 0) { sl[tid >> 6] = contrib; sv[tid >> 6] = ev; }
    __syncthreads();
    if (tid == 0) {
        ploss[blockIdx.x] = sl[0] + sl[1] + sl[2] + sl[3];
        pev[blockIdx.x]   = sv[0] + sv[1] + sv[2] + sv[3];
    }
}

// ---------------------------------------------------------------------------
// Kernel 4: final reduction of block partials -> scalar loss.
__global__ void cox_finalize(const float* __restrict__ ploss,
                             const float* __restrict__ pev,
                             float* __restrict__ out,
                             int nblocks) {
    const int tid = threadIdx.x;  // 64 threads = one wave
    float l = 0.f, v = 0.f;
    for (int k = tid; k < nblocks; k += 64) {
        l += ploss[k];
        v += pev[k];
    }
    #pragma unroll
    for (int off = 32; off > 0; off >>= 1) {
        l += __shfl_down(l, off, 64);
        v += __shfl_down(v, off, 64);
    }
    if (tid == 0) out[0] = l / fmaxf(v, 1.f);
}

// ---------------------------------------------------------------------------
extern "C" void kernel_launch(void* const* d_in, const int* in_sizes, int n_in,
                              void* d_out, int out_size, void* d_ws, size_t ws_size,
                              hipStream_t stream) {
    const float* est    = (const float*)d_in[0];
    const float* target = (const float*)d_in[1];
    float*       out    = (float*)d_out;

    const int n        = in_sizes[0];              // 16384
    const int niblocks = (n + IB - 1) / IB;        // 256 i-blocks
    const int ncblocks = (n + 255) / 256;          // 64 combine blocks

    float*  ws    = (float*)d_ws;
    float*  t     = ws;                     // [n]
    float2* te    = (float2*)(ws + n);      // [n] interleaved (t, e)
    float*  pden  = ws + 3 * n;             // [JSPLIT][n]
    float*  ploss = pden + JSPLIT * n;      // [ncblocks]
    float*  pev   = ploss + ncblocks;       // [ncblocks]

    cox_prep<<<(n + 255) / 256, 256, 0, stream>>>(est, target, t, te, n);
    dim3 grid(niblocks, JSPLIT);
    cox_denom<<<grid, IB * CHUNKS, 0, stream>>>(t, te, pden, n);
    cox_combine<<<ncblocks, 256, 0, stream>>>(est, target, pden, ploss, pev, n);
    cox_finalize<<<1, 64, 0, stream>>>(ploss, pev, out, ncblocks);
}

// Round 4
// 29.764 us; speedup vs baseline: 3.5934x; 1.5619x over previous
//
#include <hip/hip_runtime.h>
#include <cmath>

// Cox partial likelihood (Breslow) loss, N=16384.
// denom[i] = sum_j [t_j >= t_i] * exp(est_j)
// loss = sum_i ev_i * (log(denom[i]) - est[i]) / max(sum ev, 1)
//
// R4 structure: register-block i (R=8 per lane), LDS-stage j-chunk,
// wave-uniform ds_read broadcast. One (t,e) fetch feeds 512 pairs.

#define RPT    8      // i's per lane (register-blocked)
#define WAVES  8      // waves per block
#define ITILE  (64 * RPT)          // 512 i's per block
#define JSPLIT 32     // j-range split across blockIdx.y
#define JCHUNK 512    // j's per block (N / JSPLIT)
#define JWAVE  (JCHUNK / WAVES)    // 64 j's per wave

// ---------------------------------------------------------------------------
// Kernel 1: partial denom. Fuses exp() into the LDS staging phase.
// Grid: (N/ITILE, JSPLIT) = (32, 32). Block: 512 threads = 8 waves.
// Lane il holds i = ibase + il + 64*r for r=0..7. Wave w scans j-subchunk w.
__global__ __launch_bounds__(64 * WAVES)
void cox_denom(const float* __restrict__ est,
               const float* __restrict__ target,
               float* __restrict__ pden,   // [JSPLIT][n]
               int n) {
    __shared__ float2 ste[JCHUNK];          // (t_j, exp(est_j))  8B*512 = 4KB
    __shared__ float  sden[WAVES][ITILE];   // per-wave partials  16KB

    const int tid  = threadIdx.x;
    const int il   = tid & 63;
    const int wave = __builtin_amdgcn_readfirstlane(tid >> 6);
    const int ibase = blockIdx.x * ITILE;

    // ---- stage this block's j-chunk into LDS (exp fused here) ----
    {
        const int jg = blockIdx.y * JCHUNK + tid;   // tid in [0,512)
        ste[tid] = make_float2(target[2 * jg], expf(est[jg]));
    }

    // ---- per-lane i state ----
    float ti[RPT], acc[RPT];
    #pragma unroll
    for (int r = 0; r < RPT; ++r) {
        ti[r]  = target[2 * (ibase + il + 64 * r)];
        acc[r] = 0.f;
    }
    __syncthreads();

    // ---- scan this wave's 64 j's: uniform ds_read_b128 broadcast ----
    const float4* sf4 = reinterpret_cast<const float4*>(ste);
    const int fbase = (wave * JWAVE) >> 1;   // float4 index of wave's chunk
    #pragma unroll 4
    for (int it = 0; it < JWAVE / 4; ++it) {
        float4 p0 = sf4[fbase + 2 * it];      // t0,e0,t1,e1
        float4 p1 = sf4[fbase + 2 * it + 1];  // t2,e2,t3,e3
        #pragma unroll
        for (int r = 0; r < RPT; ++r) {
            acc[r] += (ti[r] <= p0.x) ? p0.y : 0.f;
            acc[r] += (ti[r] <= p0.z) ? p0.w : 0.f;
            acc[r] += (ti[r] <= p1.x) ? p1.y : 0.f;
            acc[r] += (ti[r] <= p1.z) ? p1.w : 0.f;
        }
    }

    // ---- reduce 8 waves' partials per i ----
    #pragma unroll
    for (int r = 0; r < RPT; ++r) sden[wave][(r << 6) + il] = acc[r];
    __syncthreads();

    // thread tid owns i = ibase + tid  (tid = r*64+il decomposition matches)
    float d = 0.f;
    #pragma unroll
    for (int w = 0; w < WAVES; ++w) d += sden[w][tid];
    pden[blockIdx.y * n + ibase + tid] = d;
}

// ---------------------------------------------------------------------------
// Kernel 2: combine j-split partials, per-i contribution, per-block reduce.
__global__ __launch_bounds__(256)
void cox_combine(const float* __restrict__ est,
                 const float* __restrict__ target,
                 const float* __restrict__ pden,
                 float* __restrict__ ploss,
                 float* __restrict__ pev,
                 int n) {
    __shared__ float sl[4], sv[4];
    const int tid = threadIdx.x;
    const int i   = blockIdx.x * 256 + tid;

    float d = 0.f;
    #pragma unroll
    for (int s = 0; s < JSPLIT; ++s) d += pden[s * n + i];
    float ev      = (target[2 * i + 1] != 0.f) ? 1.f : 0.f;
    float contrib = ev * (logf(d) - est[i]);

    #pragma unroll
    for (int off = 32; off > 0; off >>= 1) {
        contrib += __shfl_down(contrib, off, 64);
        ev      += __shfl_down(ev, off, 64);
    }
    if ((tid & 63) == 0) { sl[tid >> 6] = contrib; sv[tid >> 6] = ev; }
    __syncthreads();
    if (tid == 0) {
        ploss[blockIdx.x] = sl[0] + sl[1] + sl[2] + sl[3];
        pev[blockIdx.x]   = sv[0] + sv[1] + sv[2] + sv[3];
    }
}

// ---------------------------------------------------------------------------
// Kernel 3: final reduction of block partials -> scalar loss.
__global__ void cox_finalize(const float* __restrict__ ploss,
                             const float* __restrict__ pev,
                             float* __restrict__ out,
                             int nblocks) {
    const int tid = threadIdx.x;  // 64 threads = one wave
    float l = 0.f, v = 0.f;
    for (int k = tid; k < nblocks; k += 64) {
        l += ploss[k];
        v += pev[k];
    }
    #pragma unroll
    for (int off = 32; off > 0; off >>= 1) {
        l += __shfl_down(l, off, 64);
        v += __shfl_down(v, off, 64);
    }
    if (tid == 0) out[0] = l / fmaxf(v, 1.f);
}

// ---------------------------------------------------------------------------
extern "C" void kernel_launch(void* const* d_in, const int* in_sizes, int n_in,
                              void* d_out, int out_size, void* d_ws, size_t ws_size,
                              hipStream_t stream) {
    const float* est    = (const float*)d_in[0];
    const float* target = (const float*)d_in[1];
    float*       out    = (float*)d_out;

    const int n        = in_sizes[0];          // 16384
    const int niblocks = n / ITILE;            // 32
    const int ncblocks = n / 256;              // 64

    float* ws    = (float*)d_ws;
    float* pden  = ws;                         // [JSPLIT][n] = 2 MB
    float* ploss = pden + JSPLIT * n;          // [ncblocks]
    float* pev   = ploss + ncblocks;           // [ncblocks]

    dim3 grid(niblocks, JSPLIT);
    cox_denom<<<grid, 64 * WAVES, 0, stream>>>(est, target, pden, n);
    cox_combine<<<ncblocks, 256, 0, stream>>>(est, target, pden, ploss, pev, n);
    cox_finalize<<<1, 64, 0, stream>>>(ploss, pev, out, ncblocks);
}